// Round 1
// baseline (1419.533 us; speedup 1.0000x reference)
//
#include <hip/hip_runtime.h>
#include <math.h>

// ---------------------------------------------------------------------------
// FullModelPCN: FPS + Sinkhorn-EMD (x2) + Chamfer (x2) + passthrough
// B=4; N1=1024 (coarse), N2=4096 (fine/gt).
//
// Round-13 structure (prev best 1339 us):
//   Launch 1: prep
//   Launch 2: uni_kernel (grid 220, 1 block/CU):
//     blocks 0..3     : fps (signals fps-done flag per batch at end)
//     blocks 4..131   : emd2 (128, NC2=16); blocks e<64 then become emd1
//                       workers: wait fps flag, run 21 Sinkhorn rounds
//                       in-kernel with COLUMN-OWNERSHIP (each block owns 64
//                       output cols, reduces all 1024 rows itself) so the
//                       per-round cross-block traffic is a 4KB vector per
//                       batch instead of 512KB of chunk partials.
//     blocks 132..219 : chamfer
//   Launch 3: asg1_kernel (4 blocks): assign1+combine1 (reads final g vec).
//
// emd1 arithmetic is bit-identical to the old pass1 chain: same 16 chunk
// partials (8-row groups, same fmaf nesting), same finalize order; partials
// just live in LDS instead of HBM.
// ---------------------------------------------------------------------------

#define LOG2E 1.4426950408889634f
#define LN2   0.6931471805599453f
#define NEGBIG -3.0e38f

// sync region (uints, 4096, memset 0 per call):
//   emd2 slots:  b*512 + j*16           -> [0, 2048)
//   fps-done:    2048 + b*16            -> [2048, 2112)
//   emd1 slots:  2176 + b*256 + ch*16   -> [2176, 3200)
#define SY2(b) ((b) * 512)
#define SYF(b) (2048 + (b) * 16)
#define SYE(b) (2176 + (b) * 256)

#if __has_builtin(__builtin_amdgcn_exp2f)
__device__ __forceinline__ float fexp2(float x) { return __builtin_amdgcn_exp2f(x); }
#else
__device__ __forceinline__ float fexp2(float x) { return exp2f(x); }
#endif

__device__ __forceinline__ float dist_rn(float x, float y, float z,
                                         float qx, float qy, float qz) {
  float dx = __fsub_rn(x, qx), dy = __fsub_rn(y, qy), dz = __fsub_rn(z, qz);
  return __fadd_rn(__fadd_rn(__fmul_rn(dx, dx), __fmul_rn(dy, dy)),
                   __fmul_rn(dz, dz));
}

// ------------------------------ shared memory -------------------------------
struct FpsS {
  float4 sq[4096];
  unsigned sVB[2][4];
  int sII[2][4];
  float4 sQ[2][4];
  float4 sOut[64];
};
struct WorkS {
  float4 ldsRow[256];
  float4 ldsC[1024];
  float ldsG2[1024];
  float red[8];
};
struct Emd1S {
  float4 rowsO[1024];   // o1 points; .w = f-weight (odd-round rows)
  float4 rowsG[1024];   // gt_fps points; .w = g-weight (even-round rows)
  float2 part[64][17];  // per-column chunk partials (16 used, +1 pad)
};
union SmemAll {
  FpsS f;
  WorkS w;
  Emd1S e;
  float pad_force_one_block_per_cu[21504];  // 86 KB: 1 block/CU guaranteed
};

// ------------------------------ args ----------------------------------------
struct UniArgs {
  const float* gt;
  const float* epsP;
  const float4 *o1P4, *o2P4, *gtP4;
  float4* gfP4;
  float2 *gpart2, *fpart2, *apart2;
  float* vec1;  // [0,4096): g vector (gt_fps side); [4096,8192): f vector (o1)
  unsigned* sync;
  float* out;
  int NC2, BPB;
};

// ------------------- distributed-arrival relaxed barriers -------------------
__device__ __forceinline__ void bar_signal(unsigned* slot, unsigned val) {
  __syncthreads();
  if (threadIdx.x == 0)
    __hip_atomic_store(slot, val, __ATOMIC_RELEASE, __HIP_MEMORY_SCOPE_AGENT);
}
template <int SLP>
__device__ __forceinline__ void bar_waitall(const unsigned* base, int n,
                                            unsigned target) {
  if (threadIdx.x < 64) {
    int l = threadIdx.x;
    for (;;) {
      unsigned v = (l < n)
                       ? __hip_atomic_load(base + l * 16, __ATOMIC_RELAXED,
                                           __HIP_MEMORY_SCOPE_AGENT)
                       : target;
      if (__all((int)(v >= target))) break;
      __builtin_amdgcn_s_sleep(SLP);
    }
    if (l == 0)
      (void)__hip_atomic_load(base, __ATOMIC_ACQUIRE, __HIP_MEMORY_SCOPE_AGENT);
  }
  __syncthreads();
}

__device__ __forceinline__ float blockRedSum(float v, float* red4) {
#pragma unroll
  for (int m = 32; m; m >>= 1) v += __shfl_xor(v, m, 64);
  int lane = threadIdx.x & 63, wid = threadIdx.x >> 6;
  __syncthreads();
  if (lane == 0) red4[wid] = v;
  __syncthreads();
  float s = 0.0f;
  if (threadIdx.x == 0) {
#pragma unroll
    for (int w = 0; w < 4; ++w) s += red4[w];
  }
  return s;
}

// --------------------------- prep: build P4 arrays --------------------------
__global__ __launch_bounds__(256) void prep_kernel(
    const float* __restrict__ o1, const float* __restrict__ o2,
    const float* __restrict__ gt, const float* __restrict__ epsP,
    float4* __restrict__ o1P4, float4* __restrict__ o2P4,
    float4* __restrict__ gtP4) {
  int id = blockIdx.x * 256 + threadIdx.x;  // 0..36863
  float eps = *epsP;
  float se = (1.0f / eps) * LOG2E;
  float kxy = sqrtf(se + se);
  const float* src;
  float4* dst;
  if (id < 4096) { src = o1 + 3 * id; dst = o1P4 + id; }
  else if (id < 20480) { int p = id - 4096; src = o2 + 3 * p; dst = o2P4 + p; }
  else { int p = id - 20480; src = gt + 3 * p; dst = gtP4 + p; }
  float x = src[0], y = src[1], z = src[2];
  float xx = x * x + y * y + z * z;
  *dst = make_float4(kxy * x, kxy * y, kxy * z, xx * se);
}

// --------------------------- Sinkhorn LSE helpers ---------------------------
template <int NC>
__device__ __forceinline__ float finalize_w(const float2* __restrict__ part,
                                            int gi, int stride, float nloga2) {
  float2 pp[NC];
#pragma unroll
  for (int c = 0; c < NC; ++c) pp[c] = part[c * stride + gi];
  float m = pp[0].x;
#pragma unroll
  for (int c = 1; c < NC; ++c) m = fmaxf(m, pp[c].x);
  float s = 0.0f;
#pragma unroll
  for (int c = 0; c < NC; ++c) s += pp[c].y * fexp2(pp[c].x - m);
  return nloga2 - (m + __log2f(s));
}

// emd2 pass: block = (b, cb in 0..1, ch in 0..NC-1); 2048 cols (8/thread)
template <int NC>
__device__ void pass2_job(int b, int cb, int ch, const float4* __restrict__ rowP,
                          const float4* __restrict__ colP,
                          const float2* __restrict__ vpart,
                          float2* __restrict__ dst, float4* ldsRow) {
  const int CH = 4096 / NC;
  int tid = threadIdx.x;
  int gj = b * 4096 + cb * 2048 + tid;
  float cx[8], cy[8], cz[8];
#pragma unroll
  for (int c = 0; c < 8; ++c) {
    float4 cp = colP[gj + (c << 8)];
    cx[c] = cp.x; cy[c] = cp.y; cz[c] = cp.z;
  }
  float M[8], S[8];
#pragma unroll
  for (int c = 0; c < 8; ++c) { M[c] = NEGBIG; S[c] = 0.0f; }
  int r0 = ch * CH;
  for (int t0 = 0; t0 < CH; t0 += 256) {
    __syncthreads();
    {
      int gi = b * 4096 + r0 + t0 + tid;
      float4 rp = rowP[gi];
      float w = vpart ? finalize_w<NC>(vpart, gi, 16384, 12.0f) : -rp.w;
      ldsRow[tid] = make_float4(rp.x, rp.y, rp.z, w);
    }
    __syncthreads();
#pragma unroll 1
    for (int r = 0; r < 256; r += 8) {
      float4 q[8];
#pragma unroll
      for (int u = 0; u < 8; ++u) q[u] = ldsRow[r + u];
#pragma unroll
      for (int c = 0; c < 8; ++c) {
        float t[8];
#pragma unroll
        for (int u = 0; u < 8; ++u)
          t[u] = fmaf(cx[c], q[u].x, fmaf(cy[c], q[u].y, fmaf(cz[c], q[u].z, q[u].w)));
        float cm = fmaxf(fmaxf(fmaxf(t[0], t[1]), fmaxf(t[2], t[3])),
                         fmaxf(fmaxf(t[4], t[5]), fmaxf(t[6], t[7])));
        float nM = fmaxf(M[c], cm);
        float s8 = ((fexp2(t[0] - nM) + fexp2(t[1] - nM)) +
                    (fexp2(t[2] - nM) + fexp2(t[3] - nM))) +
                   ((fexp2(t[4] - nM) + fexp2(t[5] - nM)) +
                    (fexp2(t[6] - nM) + fexp2(t[7] - nM)));
        S[c] = fmaf(S[c], fexp2(M[c] - nM), s8);
        M[c] = nM;
      }
    }
  }
#pragma unroll
  for (int c = 0; c < 8; ++c)
    dst[ch * 16384 + gj + (c << 8)] = make_float2(M[c], S[c]);
}

// ------------------------------- chamfer ------------------------------------
__device__ void cham_job(const float4* __restrict__ aP, const float4* __restrict__ bP,
                         int Na, int Nb, float* outP, float* outT,
                         float scaleP, float scaleT, int b, int rb,
                         WorkS& w, const float* epsP) {
  int tid = threadIdx.x;
  int i0 = rb * 512 + tid, i1 = i0 + 256;
  float4 a0 = aP[b * Na + i0], a1 = aP[b * Na + i1];
  float m0 = 3.0e38f, m1 = 3.0e38f;
  for (int t0 = 0; t0 < Nb; t0 += 1024) {
    __syncthreads();
    for (int t = tid; t < 1024; t += 256) w.ldsC[t] = bP[b * Nb + t0 + t];
    __syncthreads();
#pragma unroll 4
    for (int t = 0; t < 1024; ++t) {
      float4 q = w.ldsC[t];
      float c0 = fmaf(-a0.z, q.z, fmaf(-a0.y, q.y, fmaf(-a0.x, q.x, q.w + a0.w)));
      float c1 = fmaf(-a1.z, q.z, fmaf(-a1.y, q.y, fmaf(-a1.x, q.x, q.w + a1.w)));
      m0 = fminf(m0, c0);
      m1 = fminf(m1, c1);
    }
  }
  float eps = *epsP;
  float inv_se = eps * LN2;
  float d0 = fmaxf(0.0f, m0 * inv_se), d1 = fmaxf(0.0f, m1 * inv_se);
  float s1 = blockRedSum(sqrtf(d0) + sqrtf(d1), w.red);
  float s2 = blockRedSum(d0 + d1, w.red);
  if (tid == 0) {
    atomicAdd(outP, s1 * scaleP);
    atomicAdd(outT, s2 * scaleT);
  }
}

__device__ void chamfer_worker(int g, const UniArgs& A, WorkS& w) {
  for (int cj = g; cj < 104; cj += 88) {
    if (cj < 32) {
      cham_job(A.gtP4, A.o2P4, 4096, 4096, A.out + 61452 + (cj >> 3),
               A.out + 61460 + (cj >> 3), 1.0f / 8192.0f, 1.0f / 4096.0f,
               cj >> 3, cj & 7, w, A.epsP);
    } else if (cj < 64) {
      int j = cj - 32;
      cham_job(A.o2P4, A.gtP4, 4096, 4096, A.out + 61452 + (j >> 3),
               A.out + 61460 + (j >> 3), 1.0f / 8192.0f, 1.0f / 4096.0f,
               j >> 3, j & 7, w, A.epsP);
    } else if (cj < 96) {
      int j = cj - 64;
      cham_job(A.gtP4, A.o1P4, 4096, 1024, A.out + 61448 + (j >> 3),
               A.out + 61456 + (j >> 3), 1.0f / 8192.0f, 1.0f / 4096.0f,
               j >> 3, j & 7, w, A.epsP);
    } else {
      int j = cj - 96;
      cham_job(A.o1P4, A.gtP4, 1024, 4096, A.out + 61448 + (j >> 1),
               A.out + 61456 + (j >> 1), 1.0f / 2048.0f, 1.0f / 1024.0f,
               j >> 1, j & 1, w, A.epsP);
    }
  }
}

// ------------------------------- assign2 ------------------------------------
template <int NC>
__device__ void assign2_job(int b, int cc, int rb, const UniArgs& A, WorkS& w) {
  int tid = threadIdx.x;
  __syncthreads();
  for (int t = tid; t < 1024; t += 256) {
    int gjc = b * 4096 + cc * 1024 + t;
    float wv = finalize_w<NC>(A.gpart2, gjc, 16384, 12.0f);
    float4 qp = A.gtP4[gjc];
    w.ldsC[t] = make_float4(qp.x, qp.y, qp.z, wv);
    w.ldsG2[t] = wv + qp.w;
  }
  __syncthreads();
#pragma unroll
  for (int rr = 0; rr < 2; ++rr) {
    int gi = b * 4096 + rb * 512 + (rr << 8) + tid;
    float4 rp = A.o2P4[gi];
    float rx = rp.x, ry = rp.y, rz = rp.z, xw = rp.w;
    float bW = NEGBIG;
    int bj = 0;
    for (int t = 0; t < 1024; ++t) {
      float4 q = w.ldsC[t];
      float W = fmaf(rz, q.z, fmaf(ry, q.y, fmaf(rx, q.x, q.w - xw)));
      W = fminf(W, w.ldsG2[t]);
      if (W > bW) { bW = W; bj = cc * 1024 + t; }
    }
    A.apart2[cc * 16384 + gi] = make_float2(bW, __int_as_float(bj));
  }
}

__device__ void combine2_job(int b, int rb, const UniArgs& A, WorkS& w) {
  int tid = threadIdx.x;
  int gi = b * 4096 + (rb << 8) + tid;
  float bW = NEGBIG;
  int bj = 0;
#pragma unroll
  for (int c = 0; c < 4; ++c) {
    float2 p = A.apart2[c * 16384 + gi];
    if (p.x > bW) { bW = p.x; bj = __float_as_int(p.y); }
  }
  float eps = *A.epsP;
  float inv_se = eps * LN2;
  float4 rp = A.o2P4[gi];
  float4 qp = A.gtP4[b * 4096 + bj];
  float dotp = rp.x * qp.x + rp.y * qp.y + rp.z * qp.z;
  float d = fmaxf(0.0f, (rp.w + qp.w - dotp) * inv_se);
  float s = blockRedSum(sqrtf(d), w.red);
  if (tid == 0) atomicAdd(A.out + 61444 + b, s * (1.0f / 4096.0f));
}

// --------------------------------- FPS --------------------------------------
// r10 logic: 256 threads, 16 pts/thread, fused min-update + depth-4
// tournament argmax, 32-bit DPP keys, parity slots, LDS out staging.
__device__ void fps_role(const UniArgs& A, int b, FpsS& f) {
  int tid = threadIdx.x;
  const float* base = A.gt + b * 12288;
  for (int t = tid; t < 4096; t += 256) {
    float x = base[3 * t], y = base[3 * t + 1], z = base[3 * t + 2];
    f.sq[t] = make_float4(x, y, z, x * x + y * y + z * z);
  }
  __syncthreads();
  float eps = *A.epsP;
  float se = (1.0f / eps) * LOG2E;
  float kxy = sqrtf(se + se);
  float4 p0 = f.sq[0];
  float px[16], py[16], pz[16], d[16];
#pragma unroll
  for (int k = 0; k < 16; ++k) {
    float4 p = f.sq[tid + (k << 8)];
    px[k] = p.x; py[k] = p.y; pz[k] = p.z;
    d[k] = dist_rn(p.x, p.y, p.z, p0.x, p0.y, p0.z);
  }
  if (tid == 0)
    f.sOut[0] = make_float4(kxy * p0.x, kxy * p0.y, kxy * p0.z, p0.w * se);
  int lane = tid & 63, wid = tid >> 6;
  float qx = p0.x, qy = p0.y, qz = p0.z;

#define DPPSTEP(C)                                                             \
  {                                                                            \
    unsigned ov = (unsigned)__builtin_amdgcn_update_dpp(0, (int)bvu, C, 0xf,  \
                                                        0xf, true);           \
    int oi = __builtin_amdgcn_update_dpp(0, bi, C, 0xf, 0xf, true);           \
    bool t = (ov > bvu) || ((ov == bvu) && ((unsigned)oi < (unsigned)bi));    \
    bvu = t ? ov : bvu;                                                        \
    bi = t ? oi : bi;                                                          \
  }
#define SCOMB(VV, II)                                                          \
  {                                                                            \
    unsigned _v = (unsigned)(VV);                                              \
    int _i = (II);                                                             \
    if (_v > wv || (_v == wv && _i < wi)) { wv = _v; wi = _i; }                \
  }
#define CCOMB(VV, II, QQ)                                                      \
  {                                                                            \
    unsigned _v = (VV);                                                        \
    int _i = (II);                                                             \
    bool t = (_v > v) || ((_v == v) && (_i < gsel));                           \
    v = t ? _v : v; gsel = t ? _i : gsel;                                      \
    nqx = t ? QQ.x : nqx; nqy = t ? QQ.y : nqy;                                \
    nqz = t ? QQ.z : nqz; nqw = t ? QQ.w : nqw;                                \
  }

  for (int s = 1; s < 1024; ++s) {
    float tv[8]; int ti[8];
#pragma unroll
    for (int i = 0; i < 8; ++i) {
      int k0 = 2 * i, k1 = 2 * i + 1;
      float n0 = fminf(d[k0], dist_rn(px[k0], py[k0], pz[k0], qx, qy, qz));
      float n1 = fminf(d[k1], dist_rn(px[k1], py[k1], pz[k1], qx, qy, qz));
      d[k0] = n0; d[k1] = n1;
      bool t = n1 > n0;
      tv[i] = t ? n1 : n0;
      ti[i] = tid + ((t ? k1 : k0) << 8);
    }
    float uv[4]; int ui[4];
#pragma unroll
    for (int i = 0; i < 4; ++i) {
      bool t = tv[2 * i + 1] > tv[2 * i];
      uv[i] = t ? tv[2 * i + 1] : tv[2 * i];
      ui[i] = t ? ti[2 * i + 1] : ti[2 * i];
    }
    bool tA = uv[1] > uv[0];
    float vA = tA ? uv[1] : uv[0]; int iA = tA ? ui[1] : ui[0];
    bool tB = uv[3] > uv[2];
    float vB = tB ? uv[3] : uv[2]; int iB = tB ? ui[3] : ui[2];
    bool tC = vB > vA;
    float bv = tC ? vB : vA; int bi = tC ? iB : iA;
    unsigned bvu = __float_as_uint(bv);
    DPPSTEP(0xB1)
    DPPSTEP(0x4E)
    DPPSTEP(0x141)
    DPPSTEP(0x140)
    unsigned wv = (unsigned)__builtin_amdgcn_readlane((int)bvu, 0);
    int wi = __builtin_amdgcn_readlane(bi, 0);
    SCOMB(__builtin_amdgcn_readlane((int)bvu, 16), __builtin_amdgcn_readlane(bi, 16))
    SCOMB(__builtin_amdgcn_readlane((int)bvu, 32), __builtin_amdgcn_readlane(bi, 32))
    SCOMB(__builtin_amdgcn_readlane((int)bvu, 48), __builtin_amdgcn_readlane(bi, 48))
    int par = s & 1;
    if (lane == 0) {
      f.sVB[par][wid] = wv;
      f.sII[par][wid] = wi;
      f.sQ[par][wid] = f.sq[wi];
    }
    __syncthreads();
    if ((s & 63) == 0 && tid < 64)
      A.gfP4[(b << 10) + (s - 64) + tid] = f.sOut[tid];
    unsigned v = f.sVB[par][0];
    int gsel = f.sII[par][0];
    float4 q0 = f.sQ[par][0], q1 = f.sQ[par][1];
    float4 q2 = f.sQ[par][2], q3 = f.sQ[par][3];
    float nqx = q0.x, nqy = q0.y, nqz = q0.z, nqw = q0.w;
    CCOMB(f.sVB[par][1], f.sII[par][1], q1)
    CCOMB(f.sVB[par][2], f.sII[par][2], q2)
    CCOMB(f.sVB[par][3], f.sII[par][3], q3)
    qx = nqx; qy = nqy; qz = nqz;
    if (tid == 0)
      f.sOut[s & 63] = make_float4(kxy * nqx, kxy * nqy, kxy * nqz, nqw * se);
  }
#undef DPPSTEP
#undef SCOMB
#undef CCOMB
  __syncthreads();
  if (tid < 64) A.gfP4[(b << 10) + 960 + tid] = f.sOut[tid];
  // publish gfP4 in-kernel for the emd1 workers (release -> L2 writeback)
  bar_signal(A.sync + SYF(b), 1u);
}

// ------------------------ emd1: in-kernel Sinkhorn --------------------------
// 16 blocks per batch; block owns 64 output columns (chunk*64..+63), reduces
// over all 1024 rows itself -> writes 64 FINAL w values per round. Chunk
// partial structure (16 x 64-row chunks, 8-row groups) and finalize order are
// bit-identical to the old pass1_kernel + finalize_w<16> chain.
__device__ void emd1_role(int eb, int chunk, const UniArgs& A, Emd1S& m) {
  int tid = threadIdx.x;
  // wait for fps of this batch (acquire -> L2 invalidate; gfP4 now visible)
  bar_waitall<16>(A.sync + SYF(eb), 1, 1u);
  // stage both row sets into LDS (xyz; rowsO.w pre-set for round 1)
  for (int t = tid; t < 1024; t += 256) {
    float4 p = A.o1P4[eb * 1024 + t];
    m.rowsO[t] = make_float4(p.x, p.y, p.z, -p.w);
    m.rowsG[t] = A.gfP4[eb * 1024 + t];  // .w overwritten before first use
  }
  int col = chunk * 64 + (tid & 63);
  int rl = tid >> 6;  // row-lane 0..3: handles chunks rl*4 .. rl*4+3
  float4 cG = A.gfP4[eb * 1024 + col];
  float4 cO = A.o1P4[eb * 1024 + col];
  float* gv = A.vec1 + (eb << 10);         // odd-round output (gt_fps side)
  float* fv = A.vec1 + 4096 + (eb << 10);  // even-round output (o1 side)
  unsigned* slots = A.sync + SYE(eb);

  for (int s = 1; s <= 21; ++s) {
    int odd = s & 1;
    if (s >= 2) {
      // refresh row weights from the previous round's vector (4KB, post-acq)
      const float* v = odd ? fv : gv;
      float4* rows = odd ? m.rowsO : m.rowsG;
      for (int t = tid; t < 1024; t += 256) rows[t].w = v[t];
    }
    __syncthreads();
    const float4* rows = odd ? m.rowsO : m.rowsG;
    float cx = odd ? cG.x : cO.x;
    float cy = odd ? cG.y : cO.y;
    float cz = odd ? cG.z : cO.z;
#pragma unroll 1
    for (int k = 0; k < 4; ++k) {
      int ch = rl * 4 + k;
      float M = NEGBIG, S = 0.0f;
      int r0 = ch * 64;
#pragma unroll 1
      for (int r = 0; r < 64; r += 8) {
        float4 q[8];
#pragma unroll
        for (int u = 0; u < 8; ++u) q[u] = rows[r0 + r + u];
        float t8[8];
#pragma unroll
        for (int u = 0; u < 8; ++u)
          t8[u] = fmaf(cx, q[u].x, fmaf(cy, q[u].y, fmaf(cz, q[u].z, q[u].w)));
        float cm = fmaxf(fmaxf(fmaxf(t8[0], t8[1]), fmaxf(t8[2], t8[3])),
                         fmaxf(fmaxf(t8[4], t8[5]), fmaxf(t8[6], t8[7])));
        float nM = fmaxf(M, cm);
        float s8 = ((fexp2(t8[0] - nM) + fexp2(t8[1] - nM)) +
                    (fexp2(t8[2] - nM) + fexp2(t8[3] - nM))) +
                   ((fexp2(t8[4] - nM) + fexp2(t8[5] - nM)) +
                    (fexp2(t8[6] - nM) + fexp2(t8[7] - nM)));
        S = fmaf(S, fexp2(M - nM), s8);
        M = nM;
      }
      m.part[tid & 63][ch] = make_float2(M, S);
    }
    __syncthreads();
    if (tid < 64) {
      // finalize: identical order to finalize_w<16>(part, ., ., 10.0f)
      float2 pp[16];
#pragma unroll
      for (int c = 0; c < 16; ++c) pp[c] = m.part[tid][c];
      float mm = pp[0].x;
#pragma unroll
      for (int c = 1; c < 16; ++c) mm = fmaxf(mm, pp[c].x);
      float ss = 0.0f;
#pragma unroll
      for (int c = 0; c < 16; ++c) ss += pp[c].y * fexp2(pp[c].x - mm);
      float w = 10.0f - (mm + __log2f(ss));
      (odd ? gv : fv)[col] = w;
    }
    bar_signal(slots + chunk * 16, (unsigned)s);
    bar_waitall<16>(slots, 16, (unsigned)s);
  }
  // round 21 (odd) g-vector is consumed by asg1_kernel (kernel boundary).
}

// ------------------------------ mega-kernel ---------------------------------
// grid 220: 0..3 fps | 4..131 emd2 (32/batch, NC2=16; e<64 continue as emd1)
// | 132..219 chamfer.
__global__ __launch_bounds__(256, 1) void uni_kernel(UniArgs A) {
  __shared__ SmemAll sm;
  int bid = blockIdx.x;
  if (bid < 4) {
    fps_role(A, bid, sm.f);
    return;
  }
  int e = bid - 4;
  int W = 4 * A.BPB;
  if (e < W) {
    int b = e / A.BPB, rest = e % A.BPB;
    int cb = rest / A.NC2, ch = rest % A.NC2;
    unsigned* slots = A.sync + SY2(b);
    for (int s = 1; s <= 21; ++s) {
      const float4 *rowP, *colP;
      const float2* vp;
      float2* dst;
      if (s & 1) { rowP = A.o2P4; colP = A.gtP4; vp = (s == 1) ? nullptr : A.fpart2; dst = A.gpart2; }
      else       { rowP = A.gtP4; colP = A.o2P4; vp = A.gpart2; dst = A.fpart2; }
      if (A.NC2 == 16) pass2_job<16>(b, cb, ch, rowP, colP, vp, dst, sm.w.ldsRow);
      else             pass2_job<8>(b, cb, ch, rowP, colP, vp, dst, sm.w.ldsRow);
      bar_signal(slots + rest * 16, (unsigned)s);
      bar_waitall<16>(slots, A.BPB, (unsigned)s);
    }
    for (int j = rest; j < 32; j += A.BPB) {
      int cc = j >> 3, rb = j & 7;
      if (A.NC2 == 16) assign2_job<16>(b, cc, rb, A, sm.w);
      else             assign2_job<8>(b, cc, rb, A, sm.w);
    }
    bar_signal(slots + rest * 16, 22u);
    bar_waitall<4>(slots, A.BPB, 22u);
    if (rest < 16) combine2_job(b, rest, A, sm.w);
    // first 64 emd2 blocks double as emd1 workers (all co-resident: grid 220)
    if (e < 64) emd1_role(e >> 4, e & 15, A, sm.e);
    return;
  }
  chamfer_worker(e - W, A, sm.w);
}

// ------------------ assign1 + combine1 standalone kernel --------------------
__global__ __launch_bounds__(256) void asg1_kernel(
    const float4* __restrict__ o1P4, const float4* __restrict__ gfP4,
    const float* __restrict__ gvec, const float* __restrict__ epsP,
    float* __restrict__ out) {
  __shared__ float4 ldsC[1024];
  __shared__ float ldsG2[1024];
  __shared__ float red[4];
  int b = blockIdx.x;
  int tid = threadIdx.x;
  for (int t = tid; t < 1024; t += 256) {
    int gjc = b * 1024 + t;
    float wv = gvec[gjc];
    float4 qp = gfP4[gjc];
    ldsC[t] = make_float4(qp.x, qp.y, qp.z, wv);
    ldsG2[t] = wv + qp.w;
  }
  __syncthreads();
  float eps = *epsP;
  float inv_se = eps * LN2;
  float vsum = 0.0f;
#pragma unroll
  for (int rr = 0; rr < 4; ++rr) {
    int gi = b * 1024 + (rr << 8) + tid;
    float4 rp = o1P4[gi];
    float rx = rp.x, ry = rp.y, rz = rp.z, xw = rp.w;
    float bW = NEGBIG;
    int bj = 0;
    for (int t = 0; t < 1024; ++t) {
      float4 q = ldsC[t];
      float W = fmaf(rz, q.z, fmaf(ry, q.y, fmaf(rx, q.x, q.w - xw)));
      W = fminf(W, ldsG2[t]);
      if (W > bW) { bW = W; bj = t; }
    }
    float4 qp = gfP4[b * 1024 + bj];
    float dotp = rp.x * qp.x + rp.y * qp.y + rp.z * qp.z;
    float d = fmaxf(0.0f, (rp.w + qp.w - dotp) * inv_se);
    vsum += sqrtf(d);
  }
  float s = blockRedSum(vsum, red);
  if (tid == 0) atomicAdd(out + 61440 + b, s * (1.0f / 1024.0f));
}

// ------------------------------ host launch ---------------------------------
extern "C" void kernel_launch(void* const* d_in, const int* in_sizes, int n_in,
                              void* d_out, int out_size, void* d_ws, size_t ws_size,
                              hipStream_t stream) {
  (void)in_sizes; (void)n_in; (void)out_size;
  const float* o1 = (const float*)d_in[0];
  const float* o2 = (const float*)d_in[1];
  const float* gt = (const float*)d_in[2];
  const float* epsP = (const float*)d_in[3];
  float* out = (float*)d_out;
  float* ws = (float*)d_ws;

  int NC2 = 16;
  {
    size_t need16 = (size_t)(4096 + 16384 + 65536 + 65536 + 16384 +
                             2 * (16 * 32768) + 2 * 131072) * 4;
    if (ws_size < need16) NC2 = 8;
  }
  size_t off = 0;
  unsigned* syncp = (unsigned*)(ws + off); off += 4096;
  float4* o1P4 = (float4*)(ws + off); off += 16384;
  float4* o2P4 = (float4*)(ws + off); off += 65536;
  float4* gtP4 = (float4*)(ws + off); off += 65536;
  float4* gfP4 = (float4*)(ws + off); off += 16384;
  float2* gpart2 = (float2*)(ws + off); off += (size_t)NC2 * 32768;
  float2* fpart2 = (float2*)(ws + off); off += (size_t)NC2 * 32768;
  float2* apart2 = fpart2;  // overlay: fpart2 dead after pass 21
  float* vec1 = (float*)(ws + off); off += 8192;  // g[4096] + f[4096]

  (void)hipMemcpyAsync(out, o1, 12288 * sizeof(float), hipMemcpyDeviceToDevice, stream);
  (void)hipMemcpyAsync(out + 12288, o2, 49152 * sizeof(float), hipMemcpyDeviceToDevice, stream);
  (void)hipMemsetAsync(out + 61440, 0, 24 * sizeof(float), stream);
  (void)hipMemsetAsync(syncp, 0, 4096 * sizeof(unsigned), stream);

  prep_kernel<<<144, 256, 0, stream>>>(o1, o2, gt, epsP, o1P4, o2P4, gtP4);

  UniArgs A;
  A.gt = gt; A.epsP = epsP;
  A.o1P4 = o1P4; A.o2P4 = o2P4; A.gtP4 = gtP4; A.gfP4 = gfP4;
  A.gpart2 = gpart2; A.fpart2 = fpart2; A.apart2 = apart2;
  A.vec1 = vec1;
  A.sync = syncp; A.out = out;
  A.NC2 = NC2; A.BPB = 2 * NC2;
  int grid = 4 + 4 * A.BPB + 88;  // 220 at NC2=16
  uni_kernel<<<grid, 256, 0, stream>>>(A);

  asg1_kernel<<<4, 256, 0, stream>>>(o1P4, gfP4, vec1, epsP, out);
}

// Round 2
// 1359.007 us; speedup vs baseline: 1.0445x; 1.0445x over previous
//
#include <hip/hip_runtime.h>
#include <math.h>

// ---------------------------------------------------------------------------
// FullModelPCN: FPS + Sinkhorn-EMD (x2) + Chamfer (x2) + passthrough
// B=4; N1=1024 (coarse), N2=4096 (fine/gt).
//
// Round-14 structure:
//   Launch 1: prep
//   Launch 2: uni_kernel (grid 220, 1 block/CU):
//     blocks 0..3     : fps (signals fps-done flag per batch at end)
//     blocks 4..131   : emd2 (128, NC2=16); blocks e<64 then become emd1
//                       workers: wait fps flag, run 21 Sinkhorn rounds via
//                       FENCELESS TAGGED-ATOMIC DATAFLOW: each of the 1024
//                       w-values is a relaxed 64-bit agent atomic (tag||val)
//                       at the LLC. No release/acquire, no buffer_inv.
//                       Chunk-0 block per batch then folds in assign1+combine1
//                       (polls tag-21 g-vector), removing the asg1 launch.
//     blocks 132..219 : chamfer
//
// emd1 arithmetic is bit-identical to the original pass1 chain: same 16
// chunk partials (8-row groups, same fmaf nesting), same finalize order.
// Safety of relaxed tagged atomics: writer reaches round s+2 (overwriting a
// tag-s slot) only after its round-s+2 refresh read all tag-s+1 values,
// which exist only after every block consumed all tag-s values.
// ---------------------------------------------------------------------------

#define LOG2E 1.4426950408889634f
#define LN2   0.6931471805599453f
#define NEGBIG -3.0e38f

// sync region (uints, 4096, memset 0 per call):
//   emd2 slots:  b*512 + j*16           -> [0, 2048)
//   fps-done:    2048 + b*16            -> [2048, 2112)
#define SY2(b) ((b) * 512)
#define SYF(b) (2048 + (b) * 16)

#if __has_builtin(__builtin_amdgcn_exp2f)
__device__ __forceinline__ float fexp2(float x) { return __builtin_amdgcn_exp2f(x); }
#else
__device__ __forceinline__ float fexp2(float x) { return exp2f(x); }
#endif

__device__ __forceinline__ float dist_rn(float x, float y, float z,
                                         float qx, float qy, float qz) {
  float dx = __fsub_rn(x, qx), dy = __fsub_rn(y, qy), dz = __fsub_rn(z, qz);
  return __fadd_rn(__fadd_rn(__fmul_rn(dx, dx), __fmul_rn(dy, dy)),
                   __fmul_rn(dz, dz));
}

// ------------------------------ shared memory -------------------------------
struct FpsS {
  float4 sq[4096];
  unsigned sVB[2][4];
  int sII[2][4];
  float4 sQ[2][4];
  float4 sOut[64];
};
struct WorkS {
  float4 ldsRow[256];
  float4 ldsC[1024];
  float ldsG2[1024];
  float red[8];
};
struct Emd1S {
  float4 rowsO[1024];   // o1 points; .w = f-weight (odd-round rows)
  float4 rowsG[1024];   // gt_fps points; .w = g-weight (even-round rows)
  float2 part[16][64];  // [chunk][col-lane] partials: wave-contiguous access
  float g2[1024];       // assign1 fold: w + |q|^2
  float red[8];
};
union SmemAll {
  FpsS f;
  WorkS w;
  Emd1S e;
  float pad_force_one_block_per_cu[21504];  // 86 KB: 1 block/CU guaranteed
};

// ------------------------------ args ----------------------------------------
struct UniArgs {
  const float* gt;
  const float* epsP;
  const float4 *o1P4, *o2P4, *gtP4;
  float4* gfP4;
  float2 *gpart2, *fpart2, *apart2;
  unsigned long long* vecT;  // [0,4096): g tagged; [4096,8192): f tagged (per-batch 1024)
  unsigned* sync;
  float* out;
  int NC2, BPB;
};

// ------------------- distributed-arrival relaxed barriers -------------------
__device__ __forceinline__ void bar_signal(unsigned* slot, unsigned val) {
  __syncthreads();
  if (threadIdx.x == 0)
    __hip_atomic_store(slot, val, __ATOMIC_RELEASE, __HIP_MEMORY_SCOPE_AGENT);
}
template <int SLP>
__device__ __forceinline__ void bar_waitall(const unsigned* base, int n,
                                            unsigned target) {
  if (threadIdx.x < 64) {
    int l = threadIdx.x;
    for (;;) {
      unsigned v = (l < n)
                       ? __hip_atomic_load(base + l * 16, __ATOMIC_RELAXED,
                                           __HIP_MEMORY_SCOPE_AGENT)
                       : target;
      if (__all((int)(v >= target))) break;
      __builtin_amdgcn_s_sleep(SLP);
    }
    if (l == 0)
      (void)__hip_atomic_load(base, __ATOMIC_ACQUIRE, __HIP_MEMORY_SCOPE_AGENT);
  }
  __syncthreads();
}

__device__ __forceinline__ float blockRedSum(float v, float* red4) {
#pragma unroll
  for (int m = 32; m; m >>= 1) v += __shfl_xor(v, m, 64);
  int lane = threadIdx.x & 63, wid = threadIdx.x >> 6;
  __syncthreads();
  if (lane == 0) red4[wid] = v;
  __syncthreads();
  float s = 0.0f;
  if (threadIdx.x == 0) {
#pragma unroll
    for (int w = 0; w < 4; ++w) s += red4[w];
  }
  return s;
}

// --------------------------- prep: build P4 arrays --------------------------
__global__ __launch_bounds__(256) void prep_kernel(
    const float* __restrict__ o1, const float* __restrict__ o2,
    const float* __restrict__ gt, const float* __restrict__ epsP,
    float4* __restrict__ o1P4, float4* __restrict__ o2P4,
    float4* __restrict__ gtP4) {
  int id = blockIdx.x * 256 + threadIdx.x;  // 0..36863
  float eps = *epsP;
  float se = (1.0f / eps) * LOG2E;
  float kxy = sqrtf(se + se);
  const float* src;
  float4* dst;
  if (id < 4096) { src = o1 + 3 * id; dst = o1P4 + id; }
  else if (id < 20480) { int p = id - 4096; src = o2 + 3 * p; dst = o2P4 + p; }
  else { int p = id - 20480; src = gt + 3 * p; dst = gtP4 + p; }
  float x = src[0], y = src[1], z = src[2];
  float xx = x * x + y * y + z * z;
  *dst = make_float4(kxy * x, kxy * y, kxy * z, xx * se);
}

// --------------------------- Sinkhorn LSE helpers ---------------------------
template <int NC>
__device__ __forceinline__ float finalize_w(const float2* __restrict__ part,
                                            int gi, int stride, float nloga2) {
  float2 pp[NC];
#pragma unroll
  for (int c = 0; c < NC; ++c) pp[c] = part[c * stride + gi];
  float m = pp[0].x;
#pragma unroll
  for (int c = 1; c < NC; ++c) m = fmaxf(m, pp[c].x);
  float s = 0.0f;
#pragma unroll
  for (int c = 0; c < NC; ++c) s += pp[c].y * fexp2(pp[c].x - m);
  return nloga2 - (m + __log2f(s));
}

// emd2 pass: block = (b, cb in 0..1, ch in 0..NC-1); 2048 cols (8/thread)
template <int NC>
__device__ void pass2_job(int b, int cb, int ch, const float4* __restrict__ rowP,
                          const float4* __restrict__ colP,
                          const float2* __restrict__ vpart,
                          float2* __restrict__ dst, float4* ldsRow) {
  const int CH = 4096 / NC;
  int tid = threadIdx.x;
  int gj = b * 4096 + cb * 2048 + tid;
  float cx[8], cy[8], cz[8];
#pragma unroll
  for (int c = 0; c < 8; ++c) {
    float4 cp = colP[gj + (c << 8)];
    cx[c] = cp.x; cy[c] = cp.y; cz[c] = cp.z;
  }
  float M[8], S[8];
#pragma unroll
  for (int c = 0; c < 8; ++c) { M[c] = NEGBIG; S[c] = 0.0f; }
  int r0 = ch * CH;
  for (int t0 = 0; t0 < CH; t0 += 256) {
    __syncthreads();
    {
      int gi = b * 4096 + r0 + t0 + tid;
      float4 rp = rowP[gi];
      float w = vpart ? finalize_w<NC>(vpart, gi, 16384, 12.0f) : -rp.w;
      ldsRow[tid] = make_float4(rp.x, rp.y, rp.z, w);
    }
    __syncthreads();
#pragma unroll 1
    for (int r = 0; r < 256; r += 8) {
      float4 q[8];
#pragma unroll
      for (int u = 0; u < 8; ++u) q[u] = ldsRow[r + u];
#pragma unroll
      for (int c = 0; c < 8; ++c) {
        float t[8];
#pragma unroll
        for (int u = 0; u < 8; ++u)
          t[u] = fmaf(cx[c], q[u].x, fmaf(cy[c], q[u].y, fmaf(cz[c], q[u].z, q[u].w)));
        float cm = fmaxf(fmaxf(fmaxf(t[0], t[1]), fmaxf(t[2], t[3])),
                         fmaxf(fmaxf(t[4], t[5]), fmaxf(t[6], t[7])));
        float nM = fmaxf(M[c], cm);
        float s8 = ((fexp2(t[0] - nM) + fexp2(t[1] - nM)) +
                    (fexp2(t[2] - nM) + fexp2(t[3] - nM))) +
                   ((fexp2(t[4] - nM) + fexp2(t[5] - nM)) +
                    (fexp2(t[6] - nM) + fexp2(t[7] - nM)));
        S[c] = fmaf(S[c], fexp2(M[c] - nM), s8);
        M[c] = nM;
      }
    }
  }
#pragma unroll
  for (int c = 0; c < 8; ++c)
    dst[ch * 16384 + gj + (c << 8)] = make_float2(M[c], S[c]);
}

// ------------------------------- chamfer ------------------------------------
__device__ void cham_job(const float4* __restrict__ aP, const float4* __restrict__ bP,
                         int Na, int Nb, float* outP, float* outT,
                         float scaleP, float scaleT, int b, int rb,
                         WorkS& w, const float* epsP) {
  int tid = threadIdx.x;
  int i0 = rb * 512 + tid, i1 = i0 + 256;
  float4 a0 = aP[b * Na + i0], a1 = aP[b * Na + i1];
  float m0 = 3.0e38f, m1 = 3.0e38f;
  for (int t0 = 0; t0 < Nb; t0 += 1024) {
    __syncthreads();
    for (int t = tid; t < 1024; t += 256) w.ldsC[t] = bP[b * Nb + t0 + t];
    __syncthreads();
#pragma unroll 4
    for (int t = 0; t < 1024; ++t) {
      float4 q = w.ldsC[t];
      float c0 = fmaf(-a0.z, q.z, fmaf(-a0.y, q.y, fmaf(-a0.x, q.x, q.w + a0.w)));
      float c1 = fmaf(-a1.z, q.z, fmaf(-a1.y, q.y, fmaf(-a1.x, q.x, q.w + a1.w)));
      m0 = fminf(m0, c0);
      m1 = fminf(m1, c1);
    }
  }
  float eps = *epsP;
  float inv_se = eps * LN2;
  float d0 = fmaxf(0.0f, m0 * inv_se), d1 = fmaxf(0.0f, m1 * inv_se);
  float s1 = blockRedSum(sqrtf(d0) + sqrtf(d1), w.red);
  float s2 = blockRedSum(d0 + d1, w.red);
  if (tid == 0) {
    atomicAdd(outP, s1 * scaleP);
    atomicAdd(outT, s2 * scaleT);
  }
}

__device__ void chamfer_worker(int g, const UniArgs& A, WorkS& w) {
  for (int cj = g; cj < 104; cj += 88) {
    if (cj < 32) {
      cham_job(A.gtP4, A.o2P4, 4096, 4096, A.out + 61452 + (cj >> 3),
               A.out + 61460 + (cj >> 3), 1.0f / 8192.0f, 1.0f / 4096.0f,
               cj >> 3, cj & 7, w, A.epsP);
    } else if (cj < 64) {
      int j = cj - 32;
      cham_job(A.o2P4, A.gtP4, 4096, 4096, A.out + 61452 + (j >> 3),
               A.out + 61460 + (j >> 3), 1.0f / 8192.0f, 1.0f / 4096.0f,
               j >> 3, j & 7, w, A.epsP);
    } else if (cj < 96) {
      int j = cj - 64;
      cham_job(A.gtP4, A.o1P4, 4096, 1024, A.out + 61448 + (j >> 3),
               A.out + 61456 + (j >> 3), 1.0f / 8192.0f, 1.0f / 4096.0f,
               j >> 3, j & 7, w, A.epsP);
    } else {
      int j = cj - 96;
      cham_job(A.o1P4, A.gtP4, 1024, 4096, A.out + 61448 + (j >> 1),
               A.out + 61456 + (j >> 1), 1.0f / 2048.0f, 1.0f / 1024.0f,
               j >> 1, j & 1, w, A.epsP);
    }
  }
}

// ------------------------------- assign2 ------------------------------------
template <int NC>
__device__ void assign2_job(int b, int cc, int rb, const UniArgs& A, WorkS& w) {
  int tid = threadIdx.x;
  __syncthreads();
  for (int t = tid; t < 1024; t += 256) {
    int gjc = b * 4096 + cc * 1024 + t;
    float wv = finalize_w<NC>(A.gpart2, gjc, 16384, 12.0f);
    float4 qp = A.gtP4[gjc];
    w.ldsC[t] = make_float4(qp.x, qp.y, qp.z, wv);
    w.ldsG2[t] = wv + qp.w;
  }
  __syncthreads();
#pragma unroll
  for (int rr = 0; rr < 2; ++rr) {
    int gi = b * 4096 + rb * 512 + (rr << 8) + tid;
    float4 rp = A.o2P4[gi];
    float rx = rp.x, ry = rp.y, rz = rp.z, xw = rp.w;
    float bW = NEGBIG;
    int bj = 0;
    for (int t = 0; t < 1024; ++t) {
      float4 q = w.ldsC[t];
      float W = fmaf(rz, q.z, fmaf(ry, q.y, fmaf(rx, q.x, q.w - xw)));
      W = fminf(W, w.ldsG2[t]);
      if (W > bW) { bW = W; bj = cc * 1024 + t; }
    }
    A.apart2[cc * 16384 + gi] = make_float2(bW, __int_as_float(bj));
  }
}

__device__ void combine2_job(int b, int rb, const UniArgs& A, WorkS& w) {
  int tid = threadIdx.x;
  int gi = b * 4096 + (rb << 8) + tid;
  float bW = NEGBIG;
  int bj = 0;
#pragma unroll
  for (int c = 0; c < 4; ++c) {
    float2 p = A.apart2[c * 16384 + gi];
    if (p.x > bW) { bW = p.x; bj = __float_as_int(p.y); }
  }
  float eps = *A.epsP;
  float inv_se = eps * LN2;
  float4 rp = A.o2P4[gi];
  float4 qp = A.gtP4[b * 4096 + bj];
  float dotp = rp.x * qp.x + rp.y * qp.y + rp.z * qp.z;
  float d = fmaxf(0.0f, (rp.w + qp.w - dotp) * inv_se);
  float s = blockRedSum(sqrtf(d), w.red);
  if (tid == 0) atomicAdd(A.out + 61444 + b, s * (1.0f / 4096.0f));
}

// --------------------------------- FPS --------------------------------------
// r10 logic: 256 threads, 16 pts/thread, fused min-update + depth-4
// tournament argmax, 32-bit DPP keys, parity slots, LDS out staging.
__device__ void fps_role(const UniArgs& A, int b, FpsS& f) {
  int tid = threadIdx.x;
  const float* base = A.gt + b * 12288;
  for (int t = tid; t < 4096; t += 256) {
    float x = base[3 * t], y = base[3 * t + 1], z = base[3 * t + 2];
    f.sq[t] = make_float4(x, y, z, x * x + y * y + z * z);
  }
  __syncthreads();
  float eps = *A.epsP;
  float se = (1.0f / eps) * LOG2E;
  float kxy = sqrtf(se + se);
  float4 p0 = f.sq[0];
  float px[16], py[16], pz[16], d[16];
#pragma unroll
  for (int k = 0; k < 16; ++k) {
    float4 p = f.sq[tid + (k << 8)];
    px[k] = p.x; py[k] = p.y; pz[k] = p.z;
    d[k] = dist_rn(p.x, p.y, p.z, p0.x, p0.y, p0.z);
  }
  if (tid == 0)
    f.sOut[0] = make_float4(kxy * p0.x, kxy * p0.y, kxy * p0.z, p0.w * se);
  int lane = tid & 63, wid = tid >> 6;
  float qx = p0.x, qy = p0.y, qz = p0.z;

#define DPPSTEP(C)                                                             \
  {                                                                            \
    unsigned ov = (unsigned)__builtin_amdgcn_update_dpp(0, (int)bvu, C, 0xf,  \
                                                        0xf, true);           \
    int oi = __builtin_amdgcn_update_dpp(0, bi, C, 0xf, 0xf, true);           \
    bool t = (ov > bvu) || ((ov == bvu) && ((unsigned)oi < (unsigned)bi));    \
    bvu = t ? ov : bvu;                                                        \
    bi = t ? oi : bi;                                                          \
  }
#define SCOMB(VV, II)                                                          \
  {                                                                            \
    unsigned _v = (unsigned)(VV);                                              \
    int _i = (II);                                                             \
    if (_v > wv || (_v == wv && _i < wi)) { wv = _v; wi = _i; }                \
  }
#define CCOMB(VV, II, QQ)                                                      \
  {                                                                            \
    unsigned _v = (VV);                                                        \
    int _i = (II);                                                             \
    bool t = (_v > v) || ((_v == v) && (_i < gsel));                           \
    v = t ? _v : v; gsel = t ? _i : gsel;                                      \
    nqx = t ? QQ.x : nqx; nqy = t ? QQ.y : nqy;                                \
    nqz = t ? QQ.z : nqz; nqw = t ? QQ.w : nqw;                                \
  }

  for (int s = 1; s < 1024; ++s) {
    float tv[8]; int ti[8];
#pragma unroll
    for (int i = 0; i < 8; ++i) {
      int k0 = 2 * i, k1 = 2 * i + 1;
      float n0 = fminf(d[k0], dist_rn(px[k0], py[k0], pz[k0], qx, qy, qz));
      float n1 = fminf(d[k1], dist_rn(px[k1], py[k1], pz[k1], qx, qy, qz));
      d[k0] = n0; d[k1] = n1;
      bool t = n1 > n0;
      tv[i] = t ? n1 : n0;
      ti[i] = tid + ((t ? k1 : k0) << 8);
    }
    float uv[4]; int ui[4];
#pragma unroll
    for (int i = 0; i < 4; ++i) {
      bool t = tv[2 * i + 1] > tv[2 * i];
      uv[i] = t ? tv[2 * i + 1] : tv[2 * i];
      ui[i] = t ? ti[2 * i + 1] : ti[2 * i];
    }
    bool tA = uv[1] > uv[0];
    float vA = tA ? uv[1] : uv[0]; int iA = tA ? ui[1] : ui[0];
    bool tB = uv[3] > uv[2];
    float vB = tB ? uv[3] : uv[2]; int iB = tB ? ui[3] : ui[2];
    bool tC = vB > vA;
    float bv = tC ? vB : vA; int bi = tC ? iB : iA;
    unsigned bvu = __float_as_uint(bv);
    DPPSTEP(0xB1)
    DPPSTEP(0x4E)
    DPPSTEP(0x141)
    DPPSTEP(0x140)
    unsigned wv = (unsigned)__builtin_amdgcn_readlane((int)bvu, 0);
    int wi = __builtin_amdgcn_readlane(bi, 0);
    SCOMB(__builtin_amdgcn_readlane((int)bvu, 16), __builtin_amdgcn_readlane(bi, 16))
    SCOMB(__builtin_amdgcn_readlane((int)bvu, 32), __builtin_amdgcn_readlane(bi, 32))
    SCOMB(__builtin_amdgcn_readlane((int)bvu, 48), __builtin_amdgcn_readlane(bi, 48))
    int par = s & 1;
    if (lane == 0) {
      f.sVB[par][wid] = wv;
      f.sII[par][wid] = wi;
      f.sQ[par][wid] = f.sq[wi];
    }
    __syncthreads();
    if ((s & 63) == 0 && tid < 64)
      A.gfP4[(b << 10) + (s - 64) + tid] = f.sOut[tid];
    unsigned v = f.sVB[par][0];
    int gsel = f.sII[par][0];
    float4 q0 = f.sQ[par][0], q1 = f.sQ[par][1];
    float4 q2 = f.sQ[par][2], q3 = f.sQ[par][3];
    float nqx = q0.x, nqy = q0.y, nqz = q0.z, nqw = q0.w;
    CCOMB(f.sVB[par][1], f.sII[par][1], q1)
    CCOMB(f.sVB[par][2], f.sII[par][2], q2)
    CCOMB(f.sVB[par][3], f.sII[par][3], q3)
    qx = nqx; qy = nqy; qz = nqz;
    if (tid == 0)
      f.sOut[s & 63] = make_float4(kxy * nqx, kxy * nqy, kxy * nqz, nqw * se);
  }
#undef DPPSTEP
#undef SCOMB
#undef CCOMB
  __syncthreads();
  if (tid < 64) A.gfP4[(b << 10) + 960 + tid] = f.sOut[tid];
  // publish gfP4 in-kernel for the emd1 workers (release -> L2 writeback)
  bar_signal(A.sync + SYF(b), 1u);
}

// ------------------------ emd1: fenceless dataflow --------------------------
// 16 blocks per batch; block owns 64 output columns, reduces all 1024 rows.
// Cross-block exchange: tagged relaxed 64-bit agent atomics (LLC, sc1) -
// no fences, no barriers, no L2 invalidates. Chunk-0 block folds in
// assign1+combine1 at the end (polls tag-21 g-vector).
__device__ void emd1_role(int eb, int chunk, const UniArgs& A, Emd1S& m) {
  int tid = threadIdx.x;
  // wait for fps of this batch (acquire once; gfP4 then readable normally)
  bar_waitall<16>(A.sync + SYF(eb), 1, 1u);
  for (int t = tid; t < 1024; t += 256) {
    float4 p = A.o1P4[eb * 1024 + t];
    m.rowsO[t] = make_float4(p.x, p.y, p.z, -p.w);
    m.rowsG[t] = A.gfP4[eb * 1024 + t];  // .w overwritten before first use
  }
  int lane = tid & 63, rl = tid >> 6;
  int col = chunk * 64 + lane;
  float4 cG = A.gfP4[eb * 1024 + col];
  float4 cO = A.o1P4[eb * 1024 + col];
  unsigned long long* gv = A.vecT + (eb << 10);          // g side (odd rounds)
  unsigned long long* fv = A.vecT + 4096 + (eb << 10);   // f side (even rounds)

  for (int s = 1; s <= 21; ++s) {
    int odd = s & 1;
    if (s >= 2) {
      // refresh row weights from the prev round's tagged vector (dataflow)
      const unsigned long long* v = odd ? fv : gv;
      float4* rows = odd ? m.rowsO : m.rowsG;
      unsigned want = (unsigned)(s - 1);
      for (int t = tid; t < 1024; t += 256) {
        unsigned long long pv;
        for (;;) {
          pv = __hip_atomic_load(v + t, __ATOMIC_RELAXED,
                                 __HIP_MEMORY_SCOPE_AGENT);
          if ((unsigned)(pv >> 32) >= want) break;
          __builtin_amdgcn_s_sleep(1);
        }
        rows[t].w = __uint_as_float((unsigned)pv);
      }
    }
    __syncthreads();
    const float4* rows = odd ? m.rowsO : m.rowsG;
    float cx = odd ? cG.x : cO.x;
    float cy = odd ? cG.y : cO.y;
    float cz = odd ? cG.z : cO.z;
#pragma unroll 1
    for (int k = 0; k < 4; ++k) {
      int ch = rl * 4 + k;
      float M = NEGBIG, S = 0.0f;
      int r0 = ch * 64;
#pragma unroll 1
      for (int r = 0; r < 64; r += 8) {
        float4 q[8];
#pragma unroll
        for (int u = 0; u < 8; ++u) q[u] = rows[r0 + r + u];
        float t8[8];
#pragma unroll
        for (int u = 0; u < 8; ++u)
          t8[u] = fmaf(cx, q[u].x, fmaf(cy, q[u].y, fmaf(cz, q[u].z, q[u].w)));
        float cm = fmaxf(fmaxf(fmaxf(t8[0], t8[1]), fmaxf(t8[2], t8[3])),
                         fmaxf(fmaxf(t8[4], t8[5]), fmaxf(t8[6], t8[7])));
        float nM = fmaxf(M, cm);
        float s8 = ((fexp2(t8[0] - nM) + fexp2(t8[1] - nM)) +
                    (fexp2(t8[2] - nM) + fexp2(t8[3] - nM))) +
                   ((fexp2(t8[4] - nM) + fexp2(t8[5] - nM)) +
                    (fexp2(t8[6] - nM) + fexp2(t8[7] - nM)));
        S = fmaf(S, fexp2(M - nM), s8);
        M = nM;
      }
      m.part[ch][lane] = make_float2(M, S);
    }
    __syncthreads();
    if (tid < 64) {
      // finalize: identical order to finalize_w<16>(part, ., ., 10.0f)
      float2 pp[16];
#pragma unroll
      for (int c = 0; c < 16; ++c) pp[c] = m.part[c][tid];
      float mm = pp[0].x;
#pragma unroll
      for (int c = 1; c < 16; ++c) mm = fmaxf(mm, pp[c].x);
      float ss = 0.0f;
#pragma unroll
      for (int c = 0; c < 16; ++c) ss += pp[c].y * fexp2(pp[c].x - mm);
      float w = 10.0f - (mm + __log2f(ss));
      unsigned long long pk = ((unsigned long long)(unsigned)s << 32) |
                              (unsigned long long)__float_as_uint(w);
      __hip_atomic_store((odd ? gv : fv) + col, pk, __ATOMIC_RELAXED,
                         __HIP_MEMORY_SCOPE_AGENT);
    }
  }
  __syncthreads();
  if (chunk != 0) return;

  // ---- assign1 + combine1 fold (bit-identical to old asg1_kernel) ----
  for (int t = tid; t < 1024; t += 256) {
    unsigned long long pv;
    for (;;) {
      pv = __hip_atomic_load(gv + t, __ATOMIC_RELAXED,
                             __HIP_MEMORY_SCOPE_AGENT);
      if ((unsigned)(pv >> 32) >= 21u) break;
      __builtin_amdgcn_s_sleep(1);
    }
    float wv = __uint_as_float((unsigned)pv);
    float4 qp = A.gfP4[eb * 1024 + t];
    m.rowsG[t] = make_float4(qp.x, qp.y, qp.z, wv);
    m.g2[t] = wv + qp.w;
  }
  __syncthreads();
  float eps = *A.epsP;
  float inv_se = eps * LN2;
  float vsum = 0.0f;
#pragma unroll
  for (int rr = 0; rr < 4; ++rr) {
    int gi = eb * 1024 + (rr << 8) + tid;
    float4 rp = A.o1P4[gi];
    float rx = rp.x, ry = rp.y, rz = rp.z, xw = rp.w;
    float bW = NEGBIG;
    int bj = 0;
    for (int t = 0; t < 1024; ++t) {
      float4 q = m.rowsG[t];
      float W = fmaf(rz, q.z, fmaf(ry, q.y, fmaf(rx, q.x, q.w - xw)));
      W = fminf(W, m.g2[t]);
      if (W > bW) { bW = W; bj = t; }
    }
    float4 qp = A.gfP4[eb * 1024 + bj];
    float dotp = rp.x * qp.x + rp.y * qp.y + rp.z * qp.z;
    float d = fmaxf(0.0f, (rp.w + qp.w - dotp) * inv_se);
    vsum += sqrtf(d);
  }
  float s = blockRedSum(vsum, m.red);
  if (tid == 0) atomicAdd(A.out + 61440 + eb, s * (1.0f / 1024.0f));
}

// ------------------------------ mega-kernel ---------------------------------
// grid 220: 0..3 fps | 4..131 emd2 (32/batch, NC2=16; e<64 continue as emd1)
// | 132..219 chamfer.
__global__ __launch_bounds__(256, 1) void uni_kernel(UniArgs A) {
  __shared__ SmemAll sm;
  int bid = blockIdx.x;
  if (bid < 4) {
    fps_role(A, bid, sm.f);
    return;
  }
  int e = bid - 4;
  int W = 4 * A.BPB;
  if (e < W) {
    int b = e / A.BPB, rest = e % A.BPB;
    int cb = rest / A.NC2, ch = rest % A.NC2;
    unsigned* slots = A.sync + SY2(b);
    for (int s = 1; s <= 21; ++s) {
      const float4 *rowP, *colP;
      const float2* vp;
      float2* dst;
      if (s & 1) { rowP = A.o2P4; colP = A.gtP4; vp = (s == 1) ? nullptr : A.fpart2; dst = A.gpart2; }
      else       { rowP = A.gtP4; colP = A.o2P4; vp = A.gpart2; dst = A.fpart2; }
      if (A.NC2 == 16) pass2_job<16>(b, cb, ch, rowP, colP, vp, dst, sm.w.ldsRow);
      else             pass2_job<8>(b, cb, ch, rowP, colP, vp, dst, sm.w.ldsRow);
      bar_signal(slots + rest * 16, (unsigned)s);
      bar_waitall<16>(slots, A.BPB, (unsigned)s);
    }
    for (int j = rest; j < 32; j += A.BPB) {
      int cc = j >> 3, rb = j & 7;
      if (A.NC2 == 16) assign2_job<16>(b, cc, rb, A, sm.w);
      else             assign2_job<8>(b, cc, rb, A, sm.w);
    }
    bar_signal(slots + rest * 16, 22u);
    bar_waitall<4>(slots, A.BPB, 22u);
    if (rest < 16) combine2_job(b, rest, A, sm.w);
    // first 64 emd2 blocks double as emd1 workers (all co-resident: grid 220)
    if (e < 64) emd1_role(e >> 4, e & 15, A, sm.e);
    return;
  }
  chamfer_worker(e - W, A, sm.w);
}

// ------------------------------ host launch ---------------------------------
extern "C" void kernel_launch(void* const* d_in, const int* in_sizes, int n_in,
                              void* d_out, int out_size, void* d_ws, size_t ws_size,
                              hipStream_t stream) {
  (void)in_sizes; (void)n_in; (void)out_size;
  const float* o1 = (const float*)d_in[0];
  const float* o2 = (const float*)d_in[1];
  const float* gt = (const float*)d_in[2];
  const float* epsP = (const float*)d_in[3];
  float* out = (float*)d_out;
  float* ws = (float*)d_ws;

  int NC2 = 16;
  {
    size_t need16 = (size_t)(4096 + 16384 + 16384 + 65536 + 65536 + 16384 +
                             2 * (16 * 32768)) * 4;
    if (ws_size < need16) NC2 = 8;
  }
  size_t off = 0;
  unsigned* syncp = (unsigned*)(ws + off); off += 4096;
  unsigned long long* vecT = (unsigned long long*)(ws + off); off += 16384;  // 8192 u64
  float4* o1P4 = (float4*)(ws + off); off += 16384;
  float4* o2P4 = (float4*)(ws + off); off += 65536;
  float4* gtP4 = (float4*)(ws + off); off += 65536;
  float4* gfP4 = (float4*)(ws + off); off += 16384;
  float2* gpart2 = (float2*)(ws + off); off += (size_t)NC2 * 32768;
  float2* fpart2 = (float2*)(ws + off); off += (size_t)NC2 * 32768;
  float2* apart2 = fpart2;  // overlay: fpart2 dead after pass 21

  (void)hipMemcpyAsync(out, o1, 12288 * sizeof(float), hipMemcpyDeviceToDevice, stream);
  (void)hipMemcpyAsync(out + 12288, o2, 49152 * sizeof(float), hipMemcpyDeviceToDevice, stream);
  (void)hipMemsetAsync(out + 61440, 0, 24 * sizeof(float), stream);
  // sync (16 KB) + vecT (64 KB) are adjacent: one memset clears both
  (void)hipMemsetAsync(syncp, 0, (4096 + 16384) * sizeof(float), stream);

  prep_kernel<<<144, 256, 0, stream>>>(o1, o2, gt, epsP, o1P4, o2P4, gtP4);

  UniArgs A;
  A.gt = gt; A.epsP = epsP;
  A.o1P4 = o1P4; A.o2P4 = o2P4; A.gtP4 = gtP4; A.gfP4 = gfP4;
  A.gpart2 = gpart2; A.fpart2 = fpart2; A.apart2 = apart2;
  A.vecT = vecT;
  A.sync = syncp; A.out = out;
  A.NC2 = NC2; A.BPB = 2 * NC2;
  int grid = 4 + 4 * A.BPB + 88;  // 220 at NC2=16
  uni_kernel<<<grid, 256, 0, stream>>>(A);
}